// Round 1
// baseline (16213.213 us; speedup 1.0000x reference)
//
#include <hip/hip_runtime.h>
#include <math.h>

constexpr float LAM = 1.0f;
constexpr int   NIT = 20;
constexpr float TOL = 1e-6f;

// scal layout (floats)
#define S_RSOLD 0
#define S_PAP   8
#define S_RSNEW 16
#define S_ALPHA 24
#define S_BETA  32
#define S_FLAG  40   // int alias

__device__ __forceinline__ float blk_reduce_256(float v){
  __shared__ float sm[4];
  #pragma unroll
  for (int o = 32; o > 0; o >>= 1) v += __shfl_down(v, o, 64);
  int lane = threadIdx.x & 63, w = threadIdx.x >> 6;
  if (lane == 0) sm[w] = v;
  __syncthreads();
  return (threadIdx.x == 0) ? (sm[0] + sm[1] + sm[2] + sm[3]) : 0.f;
}

// D := I (per-node 8x8), scal := 0
__global__ void k_setup(float* D, float* scal, int Mn){
  int i = blockIdx.x * blockDim.x + threadIdx.x;
  int stride = gridDim.x * blockDim.x;
  if (i < 64) scal[i] = 0.f;
  if (D != nullptr){
    int tot = Mn * 64;
    for (int j = i; j < tot; j += stride)
      D[j] = (((j >> 3) & 7) == (j & 7)) ? 1.f : 0.f;
  }
}

// Per edge: As = Rs^T Rs, Ad = Rd^T Rd, M = Rs^T Rd.
// D[src] += LAM*As ; D[dst] += LAM*Ad ; Mblk[e] = M.
__global__ void k_edge_pre(const float* __restrict__ Rs, const float* __restrict__ Rd,
                           const int* __restrict__ src, const int* __restrict__ dst,
                           float* __restrict__ Mblk, float* __restrict__ D, int E){
  int g  = blockIdx.x * blockDim.x + threadIdx.x;
  int wv = g >> 6, l = g & 63;
  int nw = (gridDim.x * blockDim.x) >> 6;
  int d1 = l >> 3, d2 = l & 7;
  for (int e = wv; e < E; e += nw){
    float rs = Rs[(size_t)e * 64 + l];   // lane l = (a = l>>3, d = l&7)
    float rd = Rd[(size_t)e * 64 + l];
    float As = 0.f, Ad = 0.f, Mm = 0.f;
    #pragma unroll
    for (int k = 0; k < 8; ++k){
      float s1 = __shfl(rs, k * 8 + d1, 64);  // Rs[k][d1]
      float s2 = __shfl(rs, k * 8 + d2, 64);  // Rs[k][d2]
      float t1 = __shfl(rd, k * 8 + d1, 64);  // Rd[k][d1]
      float t2 = __shfl(rd, k * 8 + d2, 64);  // Rd[k][d2]
      As += s1 * s2;
      Mm += s1 * t2;
      Ad += t1 * t2;
    }
    Mblk[(size_t)e * 64 + l] = Mm;
    int s = src[e], t = dst[e];
    atomicAdd(&D[(size_t)s * 64 + l], LAM * As);
    atomicAdd(&D[(size_t)t * 64 + l], LAM * Ad);
  }
}

// out[b,v,:] = D_v @ in[b,v,:]
__global__ void k_mv_node(const float* __restrict__ D, const float* __restrict__ in,
                          float* __restrict__ out, int Mn, const int* __restrict__ flag){
  if (*flag) return;
  int g  = blockIdx.x * blockDim.x + threadIdx.x;
  int wv = g >> 6, l = g & 63;
  int nw = (gridDim.x * blockDim.x) >> 6;
  int b = l >> 3, dd = l & 7;
  for (int v = wv; v < Mn; v += nw){
    float Dv = D[(size_t)v * 64 + l];                 // lane l = (d1,d2)
    float pv = in[((size_t)b * Mn + v) * 8 + dd];     // lane l = (b,dd)
    float acc = 0.f;
    #pragma unroll
    for (int k = 0; k < 8; ++k)
      acc += __shfl(Dv, dd * 8 + k, 64) * __shfl(pv, b * 8 + k, 64);
    out[((size_t)b * Mn + v) * 8 + dd] = acc;
  }
}

// out[b,src,:] -= LAM * M   @ in[b,dst,:]
// out[b,dst,:] -= LAM * M^T @ in[b,src,:]
__global__ void k_mv_edge(const float* __restrict__ Mblk, const int* __restrict__ src,
                          const int* __restrict__ dst, const float* __restrict__ in,
                          float* __restrict__ out, int Mn, int E, const int* __restrict__ flag){
  if (*flag) return;
  int g  = blockIdx.x * blockDim.x + threadIdx.x;
  int wv = g >> 6, l = g & 63;
  int nw = (gridDim.x * blockDim.x) >> 6;
  int b = l >> 3, dd = l & 7;
  for (int e = wv; e < E; e += nw){
    float Mm = Mblk[(size_t)e * 64 + l];              // lane l = (d1,d2)
    int s = src[e], t = dst[e];
    float ps = in[((size_t)b * Mn + s) * 8 + dd];
    float pd = in[((size_t)b * Mn + t) * 8 + dd];
    float us = 0.f, ud = 0.f;
    #pragma unroll
    for (int k = 0; k < 8; ++k){
      float mrow = __shfl(Mm, dd * 8 + k, 64);        // M[dd][k]
      float mcol = __shfl(Mm, k * 8 + dd, 64);        // M[k][dd]
      float pdk  = __shfl(pd, b * 8 + k, 64);         // in[b,dst,k]
      float psk  = __shfl(ps, b * 8 + k, 64);         // in[b,src,k]
      us += mrow * pdk;
      ud += mcol * psk;
    }
    atomicAdd(&out[((size_t)b * Mn + s) * 8 + dd], -LAM * us);
    atomicAdd(&out[((size_t)b * Mn + t) * 8 + dd], -LAM * ud);
  }
}

// fallback: Ap = in (identity part)
__global__ void k_apinit(const float* __restrict__ in, float* __restrict__ out,
                         int n4tot, const int* __restrict__ flag){
  if (*flag) return;
  int j = blockIdx.x * blockDim.x + threadIdx.x;
  if (j < n4tot) ((float4*)out)[j] = ((const float4*)in)[j];
}

// fallback: original per-edge algorithm, reads Rs/Rd directly.
__global__ void k_mv_edge_fb(const float* __restrict__ Rs, const float* __restrict__ Rd,
                             const int* __restrict__ src, const int* __restrict__ dst,
                             const float* __restrict__ in, float* __restrict__ out,
                             int Mn, int E, const int* __restrict__ flag){
  if (*flag) return;
  int g  = blockIdx.x * blockDim.x + threadIdx.x;
  int wv = g >> 6, l = g & 63;
  int nw = (gridDim.x * blockDim.x) >> 6;
  int b = l >> 3, q = l & 7;
  for (int e = wv; e < E; e += nw){
    int s = src[e], t = dst[e];
    const float4* rs4 = (const float4*)(Rs + (size_t)e * 64 + q * 8);
    const float4* rd4 = (const float4*)(Rd + (size_t)e * 64 + q * 8);
    const float4* ps4 = (const float4*)(in + ((size_t)b * Mn + s) * 8);
    const float4* pd4 = (const float4*)(in + ((size_t)b * Mn + t) * 8);
    float4 ra0 = rs4[0], ra1 = rs4[1], pa0 = ps4[0], pa1 = ps4[1];
    float4 rb0 = rd4[0], rb1 = rd4[1], pb0 = pd4[0], pb1 = pd4[1];
    // re[b][a=q] = Rs[q,:]·ps[b,:] - Rd[q,:]·pd[b,:]
    float re = ra0.x*pa0.x + ra0.y*pa0.y + ra0.z*pa0.z + ra0.w*pa0.w
             + ra1.x*pa1.x + ra1.y*pa1.y + ra1.z*pa1.z + ra1.w*pa1.w
             - (rb0.x*pb0.x + rb0.y*pb0.y + rb0.z*pb0.z + rb0.w*pb0.w
             +  rb1.x*pb1.x + rb1.y*pb1.y + rb1.z*pb1.z + rb1.w*pb1.w);
    // c_src[b,q] = sum_a Rs[a,q]*re[b,a] ; c_dst[b,q] = -sum_a Rd[a,q]*re[b,a]
    float cs = 0.f, cd = 0.f;
    #pragma unroll
    for (int a = 0; a < 8; ++a){
      float rea = __shfl(re, b * 8 + a, 64);
      cs += Rs[(size_t)e * 64 + a * 8 + q] * rea;
      cd += Rd[(size_t)e * 64 + a * 8 + q] * rea;
    }
    atomicAdd(&out[((size_t)b * Mn + s) * 8 + q],  LAM * cs);
    atomicAdd(&out[((size_t)b * Mn + t) * 8 + q], -LAM * cd);
  }
}

// x=c0, r=c0-Ap, p=r, rsold[b] += sum r^2
__global__ void k_init(const float* __restrict__ c0, const float* __restrict__ Ap,
                       float* __restrict__ x, float* __restrict__ r, float* __restrict__ p,
                       float* scal, int n4){
  int b = blockIdx.y;
  size_t base = (size_t)b * n4;
  int j = blockIdx.x * blockDim.x + threadIdx.x;
  float part = 0.f;
  if (j < n4){
    float4 cv = ((const float4*)c0)[base + j];
    float4 av = ((const float4*)Ap)[base + j];
    float4 rv = make_float4(cv.x - av.x, cv.y - av.y, cv.z - av.z, cv.w - av.w);
    ((float4*)x)[base + j] = cv;
    ((float4*)r)[base + j] = rv;
    ((float4*)p)[base + j] = rv;
    part = rv.x*rv.x + rv.y*rv.y + rv.z*rv.z + rv.w*rv.w;
  }
  float tot = blk_reduce_256(part);
  if (threadIdx.x == 0) atomicAdd(&scal[S_RSOLD + b], tot);
}

__global__ void k_dot(const float* __restrict__ p, const float* __restrict__ Ap,
                      float* scal, int n4){
  const int* flag = (const int*)(scal + S_FLAG);
  if (*flag) return;
  int b = blockIdx.y;
  size_t base = (size_t)b * n4;
  int j = blockIdx.x * blockDim.x + threadIdx.x;
  float part = 0.f;
  if (j < n4){
    float4 pv = ((const float4*)p)[base + j];
    float4 av = ((const float4*)Ap)[base + j];
    part = pv.x*av.x + pv.y*av.y + pv.z*av.z + pv.w*av.w;
  }
  float tot = blk_reduce_256(part);
  if (threadIdx.x == 0) atomicAdd(&scal[S_PAP + b], tot);
}

__global__ void k_s1(float* scal){
  const int* flag = (const int*)(scal + S_FLAG);
  if (*flag) return;
  int t = threadIdx.x;
  if (t < 8){
    scal[S_ALPHA + t] = scal[S_RSOLD + t] / (scal[S_PAP + t] + 1e-12f);
    scal[S_RSNEW + t] = 0.f;
  }
}

__global__ void k_upd(float* __restrict__ x, float* __restrict__ r,
                      const float* __restrict__ p, const float* __restrict__ Ap,
                      float* scal, int n4){
  const int* flag = (const int*)(scal + S_FLAG);
  if (*flag) return;
  int b = blockIdx.y;
  size_t base = (size_t)b * n4;
  float al = scal[S_ALPHA + b];
  int j = blockIdx.x * blockDim.x + threadIdx.x;
  float part = 0.f;
  if (j < n4){
    float4 pv = ((const float4*)p)[base + j];
    float4 av = ((const float4*)Ap)[base + j];
    float4 xv = ((float4*)x)[base + j];
    float4 rv = ((float4*)r)[base + j];
    xv.x += al * pv.x; xv.y += al * pv.y; xv.z += al * pv.z; xv.w += al * pv.w;
    rv.x -= al * av.x; rv.y -= al * av.y; rv.z -= al * av.z; rv.w -= al * av.w;
    ((float4*)x)[base + j] = xv;
    ((float4*)r)[base + j] = rv;
    part = rv.x*rv.x + rv.y*rv.y + rv.z*rv.z + rv.w*rv.w;
  }
  float tot = blk_reduce_256(part);
  if (threadIdx.x == 0) atomicAdd(&scal[S_RSNEW + b], tot);
}

__global__ void k_s2(float* scal){
  int* flag = (int*)(scal + S_FLAG);
  if (*flag) return;
  if (threadIdx.x == 0){
    float ssum = 0.f;
    for (int bb = 0; bb < 8; ++bb) ssum += scal[S_RSNEW + bb];
    if (sqrtf(ssum / 8.0f) < TOL){
      *flag = 1;  // freeze: p/rsold keep old values, later iters fully skip
    } else {
      for (int bb = 0; bb < 8; ++bb){
        scal[S_BETA + bb]  = scal[S_RSNEW + bb] / (scal[S_RSOLD + bb] + 1e-12f);
        scal[S_RSOLD + bb] = scal[S_RSNEW + bb];
        scal[S_PAP + bb]   = 0.f;
      }
    }
  }
}

__global__ void k_pupd(const float* __restrict__ r, float* __restrict__ p,
                       float* scal, int n4){
  const int* flag = (const int*)(scal + S_FLAG);
  if (*flag) return;
  int b = blockIdx.y;
  size_t base = (size_t)b * n4;
  float be = scal[S_BETA + b];
  int j = blockIdx.x * blockDim.x + threadIdx.x;
  if (j < n4){
    float4 rv = ((const float4*)r)[base + j];
    float4 pv = ((float4*)p)[base + j];
    pv.x = rv.x + be * pv.x; pv.y = rv.y + be * pv.y;
    pv.z = rv.z + be * pv.z; pv.w = rv.w + be * pv.w;
    ((float4*)p)[base + j] = pv;
  }
}

extern "C" void kernel_launch(void* const* d_in, const int* in_sizes, int n_in,
                              void* d_out, int out_size, void* d_ws, size_t ws_size,
                              hipStream_t stream){
  const float* c0 = (const float*)d_in[0];
  const int*   src = (const int*)d_in[1];
  const int*   dst = (const int*)d_in[2];
  const float* Rs = (const float*)d_in[3];
  const float* Rd = (const float*)d_in[4];

  const int B = 8, dD = 8;
  int Mn = in_sizes[0] / (B * dD);
  int E  = in_sizes[1];
  int N  = in_sizes[0];           // B*Mn*8
  int n4 = (Mn * dD) / 4;         // per-batch float4 count
  int n4tot = N / 4;

  float* ws   = (float*)d_ws;
  float* r    = ws;
  float* p    = r + N;
  float* Ap   = p + N;
  float* scal = Ap + N;
  float* D    = scal + 64;
  float* Mb   = D + (size_t)Mn * 64;

  size_t need_main = ((size_t)3 * N + 64 + (size_t)Mn * 64 + (size_t)E * 64) * 4;
  bool mainpath = (ws_size >= need_main);

  const int* flagp = (const int*)(scal + S_FLAG);

  dim3 blk(256);
  dim3 vgrid((n4 + 255) / 256, B);
  int cb = (n4tot + 255) / 256;

  k_setup<<<1024, 256, 0, stream>>>(mainpath ? D : nullptr, scal, Mn);
  if (mainpath)
    k_edge_pre<<<2048, 256, 0, stream>>>(Rs, Rd, src, dst, Mb, D, E);

  auto matvec = [&](const float* vin){
    if (mainpath){
      k_mv_node<<<512, 256, 0, stream>>>(D, vin, Ap, Mn, flagp);
      k_mv_edge<<<2048, 256, 0, stream>>>(Mb, src, dst, vin, Ap, Mn, E, flagp);
    } else {
      k_apinit<<<cb, 256, 0, stream>>>(vin, Ap, n4tot, flagp);
      k_mv_edge_fb<<<2048, 256, 0, stream>>>(Rs, Rd, src, dst, vin, Ap, Mn, E, flagp);
    }
  };

  float* x = (float*)d_out;

  matvec(c0);                                          // Ap = A c0
  k_init<<<vgrid, blk, 0, stream>>>(c0, Ap, x, r, p, scal, n4);

  for (int it = 0; it < NIT; ++it){
    matvec(p);                                         // Ap = A p
    k_dot<<<vgrid, blk, 0, stream>>>(p, Ap, scal, n4);
    k_s1<<<1, 64, 0, stream>>>(scal);
    k_upd<<<vgrid, blk, 0, stream>>>(x, r, p, Ap, scal, n4);
    k_s2<<<1, 64, 0, stream>>>(scal);
    k_pupd<<<vgrid, blk, 0, stream>>>(r, p, scal, n4);
  }
}

// Round 2
// 8854.478 us; speedup vs baseline: 1.8311x; 1.8311x over previous
//
#include <hip/hip_runtime.h>
#include <math.h>

constexpr float LAM = 1.0f;
constexpr int   NIT = 20;
constexpr float TOL = 1e-6f;

// scal layout (floats)
#define S_RSOLD 0
#define S_PAP   8
#define S_RSNEW 16
#define S_ALPHA 24
#define S_BETA  32
#define S_FLAG  40   // int alias

__device__ __forceinline__ float blk_reduce_256(float v){
  __shared__ float sm[4];
  #pragma unroll
  for (int o = 32; o > 0; o >>= 1) v += __shfl_down(v, o, 64);
  int lane = threadIdx.x & 63, w = threadIdx.x >> 6;
  if (lane == 0) sm[w] = v;
  __syncthreads();
  return (threadIdx.x == 0) ? (sm[0] + sm[1] + sm[2] + sm[3]) : 0.f;
}

// zero scal; zero cnt (csr tier); init D=I (main tier)
__global__ void k_setup(float* D, float* scal, int* cnt, int Mn){
  int i = blockIdx.x * blockDim.x + threadIdx.x;
  int stride = gridDim.x * blockDim.x;
  if (i < 64) scal[i] = 0.f;
  if (cnt != nullptr){
    for (int j = i; j < Mn; j += stride) cnt[j] = 0;
  }
  if (D != nullptr){
    int tot = Mn * 64;
    for (int j = i; j < tot; j += stride)
      D[j] = (((j >> 3) & 7) == (j & 7)) ? 1.f : 0.f;
  }
}

// ---------------- CSR tier ----------------

__global__ void k_deg(const int* __restrict__ src, const int* __restrict__ dst,
                      int* __restrict__ cnt, int E){
  int i = blockIdx.x * blockDim.x + threadIdx.x;
  int stride = gridDim.x * blockDim.x;
  for (int e = i; e < E; e += stride){
    atomicAdd(&cnt[src[e]], 1);
    atomicAdd(&cnt[dst[e]], 1);
  }
}

// single block of 1024: exclusive scan cnt -> rowptr, and cursor=rowptr
__global__ void k_scan(int* __restrict__ cnt, int* __restrict__ rowptr,
                       int* __restrict__ cursor, int Mn, int twoE){
  __shared__ int sm[1024];
  const int T = 1024;
  int t = threadIdx.x;
  int chunk = (Mn + T - 1) / T;
  int lo = t * chunk, hi = lo + chunk; if (hi > Mn) hi = Mn;
  int s = 0;
  for (int i = lo; i < hi; ++i) s += cnt[i];
  sm[t] = s;
  __syncthreads();
  for (int o = 1; o < T; o <<= 1){
    int v = (t >= o) ? sm[t - o] : 0;
    __syncthreads();
    sm[t] += v;
    __syncthreads();
  }
  int base = (t == 0) ? 0 : sm[t - 1];
  for (int i = lo; i < hi; ++i){
    int c = cnt[i];
    rowptr[i] = base;
    cursor[i] = base;
    base += c;
  }
  if (t == T - 1) rowptr[Mn] = twoE;
}

__global__ void k_fill(const int* __restrict__ src, const int* __restrict__ dst,
                       int* __restrict__ cursor, int* __restrict__ col,
                       int* __restrict__ eidside, int E){
  int i = blockIdx.x * blockDim.x + threadIdx.x;
  int stride = gridDim.x * blockDim.x;
  for (int e = i; e < E; e += stride){
    int s = src[e], t = dst[e];
    int ps = atomicAdd(&cursor[s], 1);
    col[ps] = t; eidside[ps] = (e << 1);
    int pt = atomicAdd(&cursor[t], 1);
    col[pt] = s; eidside[pt] = (e << 1) | 1;
  }
}

// wave per node: build Bcsr blocks (-lam * X^T Y) and D = I + lam*sum(X^T X)
// side0 (v=src): X=Rs, Y=Rd.  side1 (v=dst): X=Rd, Y=Rs.
__global__ void k_build(const float* __restrict__ Rs, const float* __restrict__ Rd,
                        const int* __restrict__ rowptr, const int* __restrict__ eidside,
                        float* __restrict__ Bcsr, float* __restrict__ D, int Mn){
  int g = blockIdx.x * blockDim.x + threadIdx.x;
  int v = g >> 6, l = g & 63;
  if (v >= Mn) return;
  int d1 = l >> 3, d2 = l & 7;
  float Dacc = 0.f;
  int j0 = rowptr[v], j1 = rowptr[v + 1];
  for (int j = j0; j < j1; ++j){
    int es = eidside[j];
    int e = es >> 1, side = es & 1;
    float rs = Rs[(size_t)e * 64 + l];   // lane l = (a,d) of R
    float rd = Rd[(size_t)e * 64 + l];
    float x = side ? rd : rs;
    float y = side ? rs : rd;
    float Bacc = 0.f;
    #pragma unroll
    for (int a = 0; a < 8; ++a){
      float x1 = __shfl(x, a * 8 + d1, 64);
      float x2 = __shfl(x, a * 8 + d2, 64);
      float y2 = __shfl(y, a * 8 + d2, 64);
      Bacc += x1 * y2;
      Dacc += x1 * x2;
    }
    Bcsr[(size_t)j * 64 + l] = -LAM * Bacc;
  }
  D[(size_t)v * 64 + l] = ((d1 == d2) ? 1.f : 0.f) + LAM * Dacc;
}

// wave per node, lane=(b,d): out[b,v,:] = D_v p[v] + sum_j Bcsr[j] p[col[j]]
__global__ void k_mv_csr(const float* __restrict__ D, const float* __restrict__ Bcsr,
                         const int* __restrict__ rowptr, const int* __restrict__ col,
                         const float* __restrict__ p, float* __restrict__ out,
                         int Mn, const int* __restrict__ flag){
  if (*flag) return;
  int g = blockIdx.x * blockDim.x + threadIdx.x;
  int v = g >> 6, l = g & 63;
  if (v >= Mn) return;
  int b = l >> 3, dd = l & 7;
  const float4* pv4 = (const float4*)(p + ((size_t)b * Mn + v) * 8);
  float4 pv0 = pv4[0], pv1 = pv4[1];
  const float4* dr4 = (const float4*)(D + (size_t)v * 64 + dd * 8);
  float4 dr0 = dr4[0], dr1 = dr4[1];
  float acc = dr0.x*pv0.x + dr0.y*pv0.y + dr0.z*pv0.z + dr0.w*pv0.w
            + dr1.x*pv1.x + dr1.y*pv1.y + dr1.z*pv1.z + dr1.w*pv1.w;
  int j0 = rowptr[v], j1 = rowptr[v + 1];
  for (int j = j0; j < j1; ++j){
    int c = col[j];
    const float4* br4 = (const float4*)(Bcsr + (size_t)j * 64 + dd * 8);
    float4 br0 = br4[0], br1 = br4[1];
    const float4* pc4 = (const float4*)(p + ((size_t)b * Mn + c) * 8);
    float4 pc0 = pc4[0], pc1 = pc4[1];
    acc += br0.x*pc0.x + br0.y*pc0.y + br0.z*pc0.z + br0.w*pc0.w
         + br1.x*pc1.x + br1.y*pc1.y + br1.z*pc1.z + br1.w*pc1.w;
  }
  out[((size_t)b * Mn + v) * 8 + dd] = acc;
}

// ---------------- main tier (round-1, kept as fallback) ----------------

__global__ void k_edge_pre(const float* __restrict__ Rs, const float* __restrict__ Rd,
                           const int* __restrict__ src, const int* __restrict__ dst,
                           float* __restrict__ Mblk, float* __restrict__ D, int E){
  int g  = blockIdx.x * blockDim.x + threadIdx.x;
  int wv = g >> 6, l = g & 63;
  int nw = (gridDim.x * blockDim.x) >> 6;
  int d1 = l >> 3, d2 = l & 7;
  for (int e = wv; e < E; e += nw){
    float rs = Rs[(size_t)e * 64 + l];
    float rd = Rd[(size_t)e * 64 + l];
    float As = 0.f, Ad = 0.f, Mm = 0.f;
    #pragma unroll
    for (int k = 0; k < 8; ++k){
      float s1 = __shfl(rs, k * 8 + d1, 64);
      float s2 = __shfl(rs, k * 8 + d2, 64);
      float t1 = __shfl(rd, k * 8 + d1, 64);
      float t2 = __shfl(rd, k * 8 + d2, 64);
      As += s1 * s2;
      Mm += s1 * t2;
      Ad += t1 * t2;
    }
    Mblk[(size_t)e * 64 + l] = Mm;
    int s = src[e], t = dst[e];
    atomicAdd(&D[(size_t)s * 64 + l], LAM * As);
    atomicAdd(&D[(size_t)t * 64 + l], LAM * Ad);
  }
}

__global__ void k_mv_node(const float* __restrict__ D, const float* __restrict__ in,
                          float* __restrict__ out, int Mn, const int* __restrict__ flag){
  if (*flag) return;
  int g  = blockIdx.x * blockDim.x + threadIdx.x;
  int wv = g >> 6, l = g & 63;
  int nw = (gridDim.x * blockDim.x) >> 6;
  int b = l >> 3, dd = l & 7;
  for (int v = wv; v < Mn; v += nw){
    float Dv = D[(size_t)v * 64 + l];
    float pv = in[((size_t)b * Mn + v) * 8 + dd];
    float acc = 0.f;
    #pragma unroll
    for (int k = 0; k < 8; ++k)
      acc += __shfl(Dv, dd * 8 + k, 64) * __shfl(pv, b * 8 + k, 64);
    out[((size_t)b * Mn + v) * 8 + dd] = acc;
  }
}

__global__ void k_mv_edge(const float* __restrict__ Mblk, const int* __restrict__ src,
                          const int* __restrict__ dst, const float* __restrict__ in,
                          float* __restrict__ out, int Mn, int E, const int* __restrict__ flag){
  if (*flag) return;
  int g  = blockIdx.x * blockDim.x + threadIdx.x;
  int wv = g >> 6, l = g & 63;
  int nw = (gridDim.x * blockDim.x) >> 6;
  int b = l >> 3, dd = l & 7;
  for (int e = wv; e < E; e += nw){
    float Mm = Mblk[(size_t)e * 64 + l];
    int s = src[e], t = dst[e];
    float ps = in[((size_t)b * Mn + s) * 8 + dd];
    float pd = in[((size_t)b * Mn + t) * 8 + dd];
    float us = 0.f, ud = 0.f;
    #pragma unroll
    for (int k = 0; k < 8; ++k){
      float mrow = __shfl(Mm, dd * 8 + k, 64);
      float mcol = __shfl(Mm, k * 8 + dd, 64);
      float pdk  = __shfl(pd, b * 8 + k, 64);
      float psk  = __shfl(ps, b * 8 + k, 64);
      us += mrow * pdk;
      ud += mcol * psk;
    }
    atomicAdd(&out[((size_t)b * Mn + s) * 8 + dd], -LAM * us);
    atomicAdd(&out[((size_t)b * Mn + t) * 8 + dd], -LAM * ud);
  }
}

__global__ void k_apinit(const float* __restrict__ in, float* __restrict__ out,
                         int n4tot, const int* __restrict__ flag){
  if (*flag) return;
  int j = blockIdx.x * blockDim.x + threadIdx.x;
  if (j < n4tot) ((float4*)out)[j] = ((const float4*)in)[j];
}

__global__ void k_mv_edge_fb(const float* __restrict__ Rs, const float* __restrict__ Rd,
                             const int* __restrict__ src, const int* __restrict__ dst,
                             const float* __restrict__ in, float* __restrict__ out,
                             int Mn, int E, const int* __restrict__ flag){
  if (*flag) return;
  int g  = blockIdx.x * blockDim.x + threadIdx.x;
  int wv = g >> 6, l = g & 63;
  int nw = (gridDim.x * blockDim.x) >> 6;
  int b = l >> 3, q = l & 7;
  for (int e = wv; e < E; e += nw){
    int s = src[e], t = dst[e];
    const float4* rs4 = (const float4*)(Rs + (size_t)e * 64 + q * 8);
    const float4* rd4 = (const float4*)(Rd + (size_t)e * 64 + q * 8);
    const float4* ps4 = (const float4*)(in + ((size_t)b * Mn + s) * 8);
    const float4* pd4 = (const float4*)(in + ((size_t)b * Mn + t) * 8);
    float4 ra0 = rs4[0], ra1 = rs4[1], pa0 = ps4[0], pa1 = ps4[1];
    float4 rb0 = rd4[0], rb1 = rd4[1], pb0 = pd4[0], pb1 = pd4[1];
    float re = ra0.x*pa0.x + ra0.y*pa0.y + ra0.z*pa0.z + ra0.w*pa0.w
             + ra1.x*pa1.x + ra1.y*pa1.y + ra1.z*pa1.z + ra1.w*pa1.w
             - (rb0.x*pb0.x + rb0.y*pb0.y + rb0.z*pb0.z + rb0.w*pb0.w
             +  rb1.x*pb1.x + rb1.y*pb1.y + rb1.z*pb1.z + rb1.w*pb1.w);
    float cs = 0.f, cd = 0.f;
    #pragma unroll
    for (int a = 0; a < 8; ++a){
      float rea = __shfl(re, b * 8 + a, 64);
      cs += Rs[(size_t)e * 64 + a * 8 + q] * rea;
      cd += Rd[(size_t)e * 64 + a * 8 + q] * rea;
    }
    atomicAdd(&out[((size_t)b * Mn + s) * 8 + q],  LAM * cs);
    atomicAdd(&out[((size_t)b * Mn + t) * 8 + q], -LAM * cd);
  }
}

// ---------------- CG vector kernels ----------------

__global__ void k_init(const float* __restrict__ c0, const float* __restrict__ Ap,
                       float* __restrict__ x, float* __restrict__ r, float* __restrict__ p,
                       float* scal, int n4){
  int b = blockIdx.y;
  size_t base = (size_t)b * n4;
  int j = blockIdx.x * blockDim.x + threadIdx.x;
  float part = 0.f;
  if (j < n4){
    float4 cv = ((const float4*)c0)[base + j];
    float4 av = ((const float4*)Ap)[base + j];
    float4 rv = make_float4(cv.x - av.x, cv.y - av.y, cv.z - av.z, cv.w - av.w);
    ((float4*)x)[base + j] = cv;
    ((float4*)r)[base + j] = rv;
    ((float4*)p)[base + j] = rv;
    part = rv.x*rv.x + rv.y*rv.y + rv.z*rv.z + rv.w*rv.w;
  }
  float tot = blk_reduce_256(part);
  if (threadIdx.x == 0) atomicAdd(&scal[S_RSOLD + b], tot);
}

__global__ void k_dot(const float* __restrict__ p, const float* __restrict__ Ap,
                      float* scal, int n4){
  const int* flag = (const int*)(scal + S_FLAG);
  if (*flag) return;
  int b = blockIdx.y;
  size_t base = (size_t)b * n4;
  int j = blockIdx.x * blockDim.x + threadIdx.x;
  float part = 0.f;
  if (j < n4){
    float4 pv = ((const float4*)p)[base + j];
    float4 av = ((const float4*)Ap)[base + j];
    part = pv.x*av.x + pv.y*av.y + pv.z*av.z + pv.w*av.w;
  }
  float tot = blk_reduce_256(part);
  if (threadIdx.x == 0) atomicAdd(&scal[S_PAP + b], tot);
}

__global__ void k_s1(float* scal){
  const int* flag = (const int*)(scal + S_FLAG);
  if (*flag) return;
  int t = threadIdx.x;
  if (t < 8){
    scal[S_ALPHA + t] = scal[S_RSOLD + t] / (scal[S_PAP + t] + 1e-12f);
    scal[S_RSNEW + t] = 0.f;
  }
}

__global__ void k_upd(float* __restrict__ x, float* __restrict__ r,
                      const float* __restrict__ p, const float* __restrict__ Ap,
                      float* scal, int n4){
  const int* flag = (const int*)(scal + S_FLAG);
  if (*flag) return;
  int b = blockIdx.y;
  size_t base = (size_t)b * n4;
  float al = scal[S_ALPHA + b];
  int j = blockIdx.x * blockDim.x + threadIdx.x;
  float part = 0.f;
  if (j < n4){
    float4 pv = ((const float4*)p)[base + j];
    float4 av = ((const float4*)Ap)[base + j];
    float4 xv = ((float4*)x)[base + j];
    float4 rv = ((float4*)r)[base + j];
    xv.x += al * pv.x; xv.y += al * pv.y; xv.z += al * pv.z; xv.w += al * pv.w;
    rv.x -= al * av.x; rv.y -= al * av.y; rv.z -= al * av.z; rv.w -= al * av.w;
    ((float4*)x)[base + j] = xv;
    ((float4*)r)[base + j] = rv;
    part = rv.x*rv.x + rv.y*rv.y + rv.z*rv.z + rv.w*rv.w;
  }
  float tot = blk_reduce_256(part);
  if (threadIdx.x == 0) atomicAdd(&scal[S_RSNEW + b], tot);
}

__global__ void k_s2(float* scal){
  int* flag = (int*)(scal + S_FLAG);
  if (*flag) return;
  if (threadIdx.x == 0){
    float ssum = 0.f;
    for (int bb = 0; bb < 8; ++bb) ssum += scal[S_RSNEW + bb];
    if (sqrtf(ssum / 8.0f) < TOL){
      *flag = 1;
    } else {
      for (int bb = 0; bb < 8; ++bb){
        scal[S_BETA + bb]  = scal[S_RSNEW + bb] / (scal[S_RSOLD + bb] + 1e-12f);
        scal[S_RSOLD + bb] = scal[S_RSNEW + bb];
        scal[S_PAP + bb]   = 0.f;
      }
    }
  }
}

__global__ void k_pupd(const float* __restrict__ r, float* __restrict__ p,
                       float* scal, int n4){
  const int* flag = (const int*)(scal + S_FLAG);
  if (*flag) return;
  int b = blockIdx.y;
  size_t base = (size_t)b * n4;
  float be = scal[S_BETA + b];
  int j = blockIdx.x * blockDim.x + threadIdx.x;
  if (j < n4){
    float4 rv = ((const float4*)r)[base + j];
    float4 pv = ((float4*)p)[base + j];
    pv.x = rv.x + be * pv.x; pv.y = rv.y + be * pv.y;
    pv.z = rv.z + be * pv.z; pv.w = rv.w + be * pv.w;
    ((float4*)p)[base + j] = pv;
  }
}

extern "C" void kernel_launch(void* const* d_in, const int* in_sizes, int n_in,
                              void* d_out, int out_size, void* d_ws, size_t ws_size,
                              hipStream_t stream){
  const float* c0 = (const float*)d_in[0];
  const int*   src = (const int*)d_in[1];
  const int*   dst = (const int*)d_in[2];
  const float* Rs = (const float*)d_in[3];
  const float* Rd = (const float*)d_in[4];

  const int B = 8, dD = 8;
  int Mn = in_sizes[0] / (B * dD);
  int E  = in_sizes[1];
  int N  = in_sizes[0];           // B*Mn*8 floats
  int n4 = (Mn * dD) / 4;
  int n4tot = N / 4;
  int twoE = 2 * E;

  // ---- workspace layout (units: float/int = 4B) ----
  float* ws   = (float*)d_ws;
  float* r    = ws;
  float* p    = r + N;
  float* Ap   = p + N;
  float* scal = Ap + N;
  float* D    = scal + 64;
  // csr tier extras after D:
  int rp_sz  = ((Mn + 1 + 3) / 4) * 4;
  int cur_sz = ((Mn + 3) / 4) * 4;
  int*   rowptr  = (int*)(D + (size_t)Mn * 64);
  int*   cursor  = rowptr + rp_sz;
  int*   col     = cursor + cur_sz;
  int*   eidside = col + twoE;
  float* Bcsr    = (float*)(eidside + twoE);
  // main tier: Mblk sits where csr extras start
  float* Mb = (float*)rowptr;

  size_t base_f  = (size_t)3 * N + 64 + (size_t)Mn * 64;
  size_t need_csr  = (base_f + rp_sz + cur_sz + 2ull * twoE + (size_t)twoE * 64) * 4;
  size_t need_main = (base_f + (size_t)E * 64) * 4;

  bool csr  = (ws_size >= need_csr);
  bool mainpath = !csr && (ws_size >= need_main);

  const int* flagp = (const int*)(scal + S_FLAG);

  dim3 blk(256);
  dim3 vgrid((n4 + 255) / 256, B);
  int cb = (n4tot + 255) / 256;
  int node_blocks = (Mn * 64 + 255) / 256;   // wave per node, exact

  k_setup<<<1024, 256, 0, stream>>>(mainpath ? D : nullptr, scal,
                                    csr ? cursor : nullptr, Mn);
  if (csr){
    k_deg <<<1024, 256, 0, stream>>>(src, dst, cursor, E);
    k_scan<<<1, 1024, 0, stream>>>(cursor, rowptr, cursor, Mn, twoE);
    k_fill<<<1024, 256, 0, stream>>>(src, dst, cursor, col, eidside, E);
    k_build<<<node_blocks, 256, 0, stream>>>(Rs, Rd, rowptr, eidside, Bcsr, D, Mn);
  } else if (mainpath){
    k_edge_pre<<<2048, 256, 0, stream>>>(Rs, Rd, src, dst, Mb, D, E);
  }

  auto matvec = [&](const float* vin){
    if (csr){
      k_mv_csr<<<node_blocks, 256, 0, stream>>>(D, Bcsr, rowptr, col, vin, Ap, Mn, flagp);
    } else if (mainpath){
      k_mv_node<<<512, 256, 0, stream>>>(D, vin, Ap, Mn, flagp);
      k_mv_edge<<<2048, 256, 0, stream>>>(Mb, src, dst, vin, Ap, Mn, E, flagp);
    } else {
      k_apinit<<<cb, 256, 0, stream>>>(vin, Ap, n4tot, flagp);
      k_mv_edge_fb<<<2048, 256, 0, stream>>>(Rs, Rd, src, dst, vin, Ap, Mn, E, flagp);
    }
  };

  float* x = (float*)d_out;

  matvec(c0);
  k_init<<<vgrid, blk, 0, stream>>>(c0, Ap, x, r, p, scal, n4);

  for (int it = 0; it < NIT; ++it){
    matvec(p);
    k_dot<<<vgrid, blk, 0, stream>>>(p, Ap, scal, n4);
    k_s1<<<1, 64, 0, stream>>>(scal);
    k_upd<<<vgrid, blk, 0, stream>>>(x, r, p, Ap, scal, n4);
    k_s2<<<1, 64, 0, stream>>>(scal);
    k_pupd<<<vgrid, blk, 0, stream>>>(r, p, scal, n4);
  }
}

// Round 3
// 6803.634 us; speedup vs baseline: 2.3830x; 1.3014x over previous
//
#include <hip/hip_runtime.h>
#include <math.h>

constexpr float LAM = 1.0f;
constexpr int   NIT = 20;
constexpr float TOL = 1e-6f;

// ---------------- node-major (main) scal layout (floats) ----------------
#define S_RSOLD 0
#define S_BETA  8
#define S_FLAG  16        // int alias
#define S_PAP   32        // [8][256] partial slots for p.Ap
#define S_RS    (32+2048) // [8][256] partial slots for r.r
#define SCAL_F  (32+4096)

__device__ __forceinline__ float dot8(float4 a0, float4 a1, float4 b0, float4 b1){
  return a0.x*b0.x + a0.y*b0.y + a0.z*b0.z + a0.w*b0.w
       + a1.x*b1.x + a1.y*b1.y + a1.z*b1.z + a1.w*b1.w;
}

// zero scal, zero cursor, D := I
__global__ void k_setup_nm(float* __restrict__ D, float* __restrict__ scal,
                           int* __restrict__ cursor, int Mn){
  int i = blockIdx.x * blockDim.x + threadIdx.x;
  int stride = gridDim.x * blockDim.x;
  for (int j = i; j < SCAL_F; j += stride) scal[j] = 0.f;
  for (int j = i; j < Mn; j += stride) cursor[j] = 0;
  int tot = Mn * 64;
  for (int j = i; j < tot; j += stride)
    D[j] = (((j >> 3) & 7) == (j & 7)) ? 1.f : 0.f;
}

__global__ void k_deg(const int* __restrict__ src, const int* __restrict__ dst,
                      int* __restrict__ cnt, int E){
  int i = blockIdx.x * blockDim.x + threadIdx.x;
  int stride = gridDim.x * blockDim.x;
  for (int e = i; e < E; e += stride){
    atomicAdd(&cnt[src[e]], 1);
    atomicAdd(&cnt[dst[e]], 1);
  }
}

// single block of 1024: exclusive scan cnt -> rowptr, cursor=rowptr (cnt==cursor ok)
__global__ void k_scan(int* __restrict__ cnt, int* __restrict__ rowptr,
                       int* __restrict__ cursor, int Mn, int twoE){
  __shared__ int sm[1024];
  const int T = 1024;
  int t = threadIdx.x;
  int chunk = (Mn + T - 1) / T;
  int lo = t * chunk, hi = lo + chunk; if (hi > Mn) hi = Mn;
  int s = 0;
  for (int i = lo; i < hi; ++i) s += cnt[i];
  sm[t] = s;
  __syncthreads();
  for (int o = 1; o < T; o <<= 1){
    int v = (t >= o) ? sm[t - o] : 0;
    __syncthreads();
    sm[t] += v;
    __syncthreads();
  }
  int base = (t == 0) ? 0 : sm[t - 1];
  for (int i = lo; i < hi; ++i){
    int c = cnt[i];
    rowptr[i] = base;
    cursor[i] = base;
    base += c;
  }
  if (t == T - 1) rowptr[Mn] = twoE;
}

// fill CSR slots: pair[slot] = (partner_node, (e<<1)|side)
__global__ void k_fill2(const int* __restrict__ src, const int* __restrict__ dst,
                        int* __restrict__ cursor, int2* __restrict__ pair, int E){
  int i = blockIdx.x * blockDim.x + threadIdx.x;
  int stride = gridDim.x * blockDim.x;
  for (int e = i; e < E; e += stride){
    int s = src[e], t = dst[e];
    int ps = atomicAdd(&cursor[s], 1);
    pair[ps] = make_int2(t, (e << 1));
    int pt = atomicAdd(&cursor[t], 1);
    pair[pt] = make_int2(s, (e << 1) | 1);
  }
}

// wave per edge: M = Rs^T Rd (written once); D[src] += LAM*Rs^T Rs; D[dst] += LAM*Rd^T Rd
__global__ void k_edgeM(const float* __restrict__ Rs, const float* __restrict__ Rd,
                        const int* __restrict__ src, const int* __restrict__ dst,
                        float* __restrict__ Mb, float* __restrict__ D, int E){
  int g  = blockIdx.x * blockDim.x + threadIdx.x;
  int wv = g >> 6, l = g & 63;
  int nw = (gridDim.x * blockDim.x) >> 6;
  int d1 = l >> 3, d2 = l & 7;
  for (int e = wv; e < E; e += nw){
    float rs = Rs[(size_t)e * 64 + l];   // lane l = (a,d) of R
    float rd = Rd[(size_t)e * 64 + l];
    float As = 0.f, Ad = 0.f, Mm = 0.f;
    #pragma unroll
    for (int a = 0; a < 8; ++a){
      float s1 = __shfl(rs, a * 8 + d1, 64);
      float s2 = __shfl(rs, a * 8 + d2, 64);
      float t1 = __shfl(rd, a * 8 + d1, 64);
      float t2 = __shfl(rd, a * 8 + d2, 64);
      As += s1 * s2;
      Ad += t1 * t2;
      Mm += s1 * t2;
    }
    Mb[(size_t)e * 64 + l] = Mm;
    int s = src[e], t = dst[e];
    atomicAdd(&D[(size_t)s * 64 + l], LAM * As);
    atomicAdd(&D[(size_t)t * 64 + l], LAM * Ad);
  }
}

// apply M (side0) or M^T (side1) to the partner p-row held as 2 float4
__device__ __forceinline__ float applyM(const float* __restrict__ Mb, int es, int dd,
                                        float4 p0, float4 p1){
  const float* Me = Mb + (size_t)(es >> 1) * 64;
  if ((es & 1) == 0){
    float4 m0 = *(const float4*)(Me + dd * 8);
    float4 m1 = *(const float4*)(Me + dd * 8 + 4);
    return dot8(m0, m1, p0, p1);
  } else {
    return Me[dd]      * p0.x + Me[dd +  8] * p0.y + Me[dd + 16] * p0.z + Me[dd + 24] * p0.w
         + Me[dd + 32] * p1.x + Me[dd + 40] * p1.y + Me[dd + 48] * p1.z + Me[dd + 56] * p1.w;
  }
}

// wave per node, lane l=(b*8+dd): Ap[v] = D_v p_v - LAM * sum_j (M|M^T) p_col
// fused: accumulates p.Ap partials into S_PAP slots
__global__ void k_mv(const float* __restrict__ D, const float* __restrict__ Mb,
                     const int* __restrict__ rowptr, const int2* __restrict__ pair,
                     const float* __restrict__ p, float* __restrict__ out,
                     float* __restrict__ scal, int Mn){
  if (*(const int*)(scal + S_FLAG)) return;
  int g = blockIdx.x * blockDim.x + threadIdx.x;
  int v = g >> 6;
  if (v >= Mn) return;
  int l = g & 63, b = l >> 3, dd = l & 7;
  const float4* pv4 = (const float4*)(p + (size_t)v * 64 + b * 8);
  float4 pv0 = pv4[0], pv1 = pv4[1];
  const float4* dr4 = (const float4*)(D + (size_t)v * 64 + dd * 8);
  float acc = dot8(dr4[0], dr4[1], pv0, pv1);
  int j0 = rowptr[v], j1 = rowptr[v + 1];
  int j = j0;
  for (; j + 4 <= j1; j += 4){
    int2 c0 = pair[j], c1 = pair[j + 1], c2 = pair[j + 2], c3 = pair[j + 3];
    const float4* q0 = (const float4*)(p + (size_t)c0.x * 64 + b * 8);
    const float4* q1 = (const float4*)(p + (size_t)c1.x * 64 + b * 8);
    const float4* q2 = (const float4*)(p + (size_t)c2.x * 64 + b * 8);
    const float4* q3 = (const float4*)(p + (size_t)c3.x * 64 + b * 8);
    float4 a0 = q0[0], a1 = q0[1];
    float4 b0 = q1[0], b1 = q1[1];
    float4 e0 = q2[0], e1 = q2[1];
    float4 f0 = q3[0], f1 = q3[1];
    acc -= LAM * applyM(Mb, c0.y, dd, a0, a1);
    acc -= LAM * applyM(Mb, c1.y, dd, b0, b1);
    acc -= LAM * applyM(Mb, c2.y, dd, e0, e1);
    acc -= LAM * applyM(Mb, c3.y, dd, f0, f1);
  }
  for (; j < j1; ++j){
    int2 ce = pair[j];
    const float4* q = (const float4*)(p + (size_t)ce.x * 64 + b * 8);
    float4 g0 = q[0], g1 = q[1];
    acc -= LAM * applyM(Mb, ce.y, dd, g0, g1);
  }
  out[(size_t)v * 64 + l] = acc;
  // fused p.Ap: lane's own p element
  float pself = (dd & 4) ? ((dd & 2) ? ((dd & 1) ? pv1.w : pv1.z)
                                     : ((dd & 1) ? pv1.y : pv1.x))
                         : ((dd & 2) ? ((dd & 1) ? pv0.w : pv0.z)
                                     : ((dd & 1) ? pv0.y : pv0.x));
  float part = pself * acc;
  part += __shfl_xor(part, 1, 64);
  part += __shfl_xor(part, 2, 64);
  part += __shfl_xor(part, 4, 64);
  if (dd == 0)
    atomicAdd(&scal[S_PAP + b * 256 + (blockIdx.x & 255)], part);
}

// c0 (batch-major) -> x_ws (node-major)
__global__ void k_perm(const float* __restrict__ c0, float* __restrict__ xp, int Mn){
  int i = blockIdx.x * blockDim.x + threadIdx.x;
  int n4 = Mn * 16;
  if (i >= n4) return;
  int v = i >> 4, rem = i & 15, b = rem >> 1, half = rem & 1;
  float4 cv = *(const float4*)(c0 + ((size_t)b * Mn + v) * 8 + half * 4);
  ((float4*)xp)[i] = cv;
}

// x_ws (node-major) -> d_out (batch-major)
__global__ void k_export(const float* __restrict__ xp, float* __restrict__ out, int Mn){
  int i = blockIdx.x * blockDim.x + threadIdx.x;
  int n4 = Mn * 16;
  if (i >= n4) return;
  int b = i / (Mn * 2);
  int rem2 = i - b * (Mn * 2);
  int v = rem2 >> 1, half = rem2 & 1;
  float4 xv = *(const float4*)(xp + (size_t)v * 64 + b * 8 + half * 4);
  ((float4*)out)[i] = xv;
}

// r = c0p - Ap; p = r; accumulate r.r into S_RS slots
__global__ void k_init_nm(const float* __restrict__ c0p, const float* __restrict__ Ap,
                          float* __restrict__ r, float* __restrict__ p,
                          float* __restrict__ scal, int n4tot){
  int i = blockIdx.x * blockDim.x + threadIdx.x;
  int l = threadIdx.x & 63;
  float part = 0.f;
  if (i < n4tot){
    float4 cv = ((const float4*)c0p)[i];
    float4 av = ((const float4*)Ap)[i];
    float4 rv = make_float4(cv.x - av.x, cv.y - av.y, cv.z - av.z, cv.w - av.w);
    ((float4*)r)[i] = rv;
    ((float4*)p)[i] = rv;
    part = rv.x*rv.x + rv.y*rv.y + rv.z*rv.z + rv.w*rv.w;
  }
  part += __shfl_xor(part, 1, 64);
  part += __shfl_xor(part, 16, 64);
  part += __shfl_xor(part, 32, 64);
  if ((l & 49) == 0)
    atomicAdd(&scal[S_RS + ((l >> 1) & 7) * 256 + (blockIdx.x & 255)], part);
}

// once: RSOLD[b] = sum(S_RS slots); zero both slot arrays
__global__ void k_s0(float* __restrict__ scal){
  __shared__ float sm[256];
  int t = threadIdx.x;
  int b = t >> 5, k0 = t & 31;
  float s = 0.f;
  #pragma unroll
  for (int i = 0; i < 8; ++i) s += scal[S_RS + b * 256 + k0 + i * 32];
  sm[t] = s;
  __syncthreads();
  if (t < 8){
    float tot = 0.f;
    #pragma unroll
    for (int i = 0; i < 32; ++i) tot += sm[t * 32 + i];
    scal[S_RSOLD + t] = tot;
  }
  __syncthreads();
  for (int i = t; i < 4096; i += 256) scal[S_PAP + i] = 0.f;
}

// x += a p; r -= a Ap; accumulate rnew.rnew into S_RS slots (alpha from S_PAP slots)
__global__ void k_upd_nm(float* __restrict__ x, float* __restrict__ r,
                         const float* __restrict__ p, const float* __restrict__ Ap,
                         float* __restrict__ scal, int n4tot){
  if (*(const int*)(scal + S_FLAG)) return;
  __shared__ float sal[8];
  int t = threadIdx.x;
  if (t < 8){
    float s = 0.f;
    const float* pp = scal + S_PAP + t * 256;
    #pragma unroll 4
    for (int k = 0; k < 256; ++k) s += pp[k];
    sal[t] = scal[S_RSOLD + t] / (s + 1e-12f);
  }
  __syncthreads();
  int i = blockIdx.x * blockDim.x + t;
  int l = t & 63;
  float part = 0.f;
  if (i < n4tot){
    int b = (i >> 1) & 7;
    float al = sal[b];
    float4 pv = ((const float4*)p)[i];
    float4 av = ((const float4*)Ap)[i];
    float4 xv = ((float4*)x)[i];
    float4 rv = ((float4*)r)[i];
    xv.x += al * pv.x; xv.y += al * pv.y; xv.z += al * pv.z; xv.w += al * pv.w;
    rv.x -= al * av.x; rv.y -= al * av.y; rv.z -= al * av.z; rv.w -= al * av.w;
    ((float4*)x)[i] = xv;
    ((float4*)r)[i] = rv;
    part = rv.x*rv.x + rv.y*rv.y + rv.z*rv.z + rv.w*rv.w;
  }
  part += __shfl_xor(part, 1, 64);
  part += __shfl_xor(part, 16, 64);
  part += __shfl_xor(part, 32, 64);
  if ((l & 49) == 0)
    atomicAdd(&scal[S_RS + ((l >> 1) & 7) * 256 + (blockIdx.x & 255)], part);
}

// rsnew from S_RS slots; conv check/flag; BETA, RSOLD; zero both slot arrays
__global__ void k_s2(float* __restrict__ scal){
  if (*(const int*)(scal + S_FLAG)) return;
  __shared__ float sm[256];
  __shared__ float rsn[8];
  int t = threadIdx.x;
  int b = t >> 5, k0 = t & 31;
  float s = 0.f;
  #pragma unroll
  for (int i = 0; i < 8; ++i) s += scal[S_RS + b * 256 + k0 + i * 32];
  sm[t] = s;
  __syncthreads();
  if (t < 8){
    float tot = 0.f;
    #pragma unroll
    for (int i = 0; i < 32; ++i) tot += sm[t * 32 + i];
    rsn[t] = tot;
  }
  __syncthreads();
  if (t == 0){
    float ssum = 0.f;
    for (int bb = 0; bb < 8; ++bb) ssum += rsn[bb];
    if (sqrtf(ssum / 8.0f) < TOL){
      *(int*)(scal + S_FLAG) = 1;   // freeze p/rsold; later iters fully skip
    } else {
      for (int bb = 0; bb < 8; ++bb){
        scal[S_BETA + bb]  = rsn[bb] / (scal[S_RSOLD + bb] + 1e-12f);
        scal[S_RSOLD + bb] = rsn[bb];
      }
    }
  }
  __syncthreads();
  for (int i = t; i < 4096; i += 256) scal[S_PAP + i] = 0.f;
}

__global__ void k_pupd_nm(const float* __restrict__ r, float* __restrict__ p,
                          const float* __restrict__ scal, int n4tot){
  if (*(const int*)(scal + S_FLAG)) return;
  int i = blockIdx.x * blockDim.x + threadIdx.x;
  if (i >= n4tot) return;
  int b = (i >> 1) & 7;
  float be = scal[S_BETA + b];
  float4 rv = ((const float4*)r)[i];
  float4 pv = ((float4*)p)[i];
  pv.x = rv.x + be * pv.x; pv.y = rv.y + be * pv.y;
  pv.z = rv.z + be * pv.z; pv.w = rv.w + be * pv.w;
  ((float4*)p)[i] = pv;
}

// ---------------- minimal fallback tier (batch-major, R-direct) ----------------
#define OS_RSOLD 0
#define OS_PAP   8
#define OS_RSNEW 16
#define OS_ALPHA 24
#define OS_BETA  32
#define OS_FLAG  40

__device__ __forceinline__ float blk_reduce_256(float v){
  __shared__ float sm[4];
  #pragma unroll
  for (int o = 32; o > 0; o >>= 1) v += __shfl_down(v, o, 64);
  int lane = threadIdx.x & 63, w = threadIdx.x >> 6;
  if (lane == 0) sm[w] = v;
  __syncthreads();
  return (threadIdx.x == 0) ? (sm[0] + sm[1] + sm[2] + sm[3]) : 0.f;
}

__global__ void k_setup_fb(float* scal){
  int i = blockIdx.x * blockDim.x + threadIdx.x;
  if (i < 64) scal[i] = 0.f;
}

__global__ void k_apinit(const float* __restrict__ in, float* __restrict__ out,
                         int n4tot, const int* __restrict__ flag){
  if (*flag) return;
  int j = blockIdx.x * blockDim.x + threadIdx.x;
  if (j < n4tot) ((float4*)out)[j] = ((const float4*)in)[j];
}

__global__ void k_mv_edge_fb(const float* __restrict__ Rs, const float* __restrict__ Rd,
                             const int* __restrict__ src, const int* __restrict__ dst,
                             const float* __restrict__ in, float* __restrict__ out,
                             int Mn, int E, const int* __restrict__ flag){
  if (*flag) return;
  int g  = blockIdx.x * blockDim.x + threadIdx.x;
  int wv = g >> 6, l = g & 63;
  int nw = (gridDim.x * blockDim.x) >> 6;
  int b = l >> 3, q = l & 7;
  for (int e = wv; e < E; e += nw){
    int s = src[e], t = dst[e];
    const float4* rs4 = (const float4*)(Rs + (size_t)e * 64 + q * 8);
    const float4* rd4 = (const float4*)(Rd + (size_t)e * 64 + q * 8);
    const float4* ps4 = (const float4*)(in + ((size_t)b * Mn + s) * 8);
    const float4* pd4 = (const float4*)(in + ((size_t)b * Mn + t) * 8);
    float4 ra0 = rs4[0], ra1 = rs4[1], pa0 = ps4[0], pa1 = ps4[1];
    float4 rb0 = rd4[0], rb1 = rd4[1], pb0 = pd4[0], pb1 = pd4[1];
    float re = dot8(ra0, ra1, pa0, pa1) - dot8(rb0, rb1, pb0, pb1);
    float cs = 0.f, cd = 0.f;
    #pragma unroll
    for (int a = 0; a < 8; ++a){
      float rea = __shfl(re, b * 8 + a, 64);
      cs += Rs[(size_t)e * 64 + a * 8 + q] * rea;
      cd += Rd[(size_t)e * 64 + a * 8 + q] * rea;
    }
    atomicAdd(&out[((size_t)b * Mn + s) * 8 + q],  LAM * cs);
    atomicAdd(&out[((size_t)b * Mn + t) * 8 + q], -LAM * cd);
  }
}

__global__ void k_init_o(const float* __restrict__ c0, const float* __restrict__ Ap,
                         float* __restrict__ x, float* __restrict__ r, float* __restrict__ p,
                         float* scal, int n4){
  int b = blockIdx.y;
  size_t base = (size_t)b * n4;
  int j = blockIdx.x * blockDim.x + threadIdx.x;
  float part = 0.f;
  if (j < n4){
    float4 cv = ((const float4*)c0)[base + j];
    float4 av = ((const float4*)Ap)[base + j];
    float4 rv = make_float4(cv.x - av.x, cv.y - av.y, cv.z - av.z, cv.w - av.w);
    ((float4*)x)[base + j] = cv;
    ((float4*)r)[base + j] = rv;
    ((float4*)p)[base + j] = rv;
    part = rv.x*rv.x + rv.y*rv.y + rv.z*rv.z + rv.w*rv.w;
  }
  float tot = blk_reduce_256(part);
  if (threadIdx.x == 0) atomicAdd(&scal[OS_RSOLD + b], tot);
}

__global__ void k_dot_o(const float* __restrict__ p, const float* __restrict__ Ap,
                        float* scal, int n4){
  const int* flag = (const int*)(scal + OS_FLAG);
  if (*flag) return;
  int b = blockIdx.y;
  size_t base = (size_t)b * n4;
  int j = blockIdx.x * blockDim.x + threadIdx.x;
  float part = 0.f;
  if (j < n4){
    float4 pv = ((const float4*)p)[base + j];
    float4 av = ((const float4*)Ap)[base + j];
    part = pv.x*av.x + pv.y*av.y + pv.z*av.z + pv.w*av.w;
  }
  float tot = blk_reduce_256(part);
  if (threadIdx.x == 0) atomicAdd(&scal[OS_PAP + b], tot);
}

__global__ void k_s1_o(float* scal){
  const int* flag = (const int*)(scal + OS_FLAG);
  if (*flag) return;
  int t = threadIdx.x;
  if (t < 8){
    scal[OS_ALPHA + t] = scal[OS_RSOLD + t] / (scal[OS_PAP + t] + 1e-12f);
    scal[OS_RSNEW + t] = 0.f;
  }
}

__global__ void k_upd_o(float* __restrict__ x, float* __restrict__ r,
                        const float* __restrict__ p, const float* __restrict__ Ap,
                        float* scal, int n4){
  const int* flag = (const int*)(scal + OS_FLAG);
  if (*flag) return;
  int b = blockIdx.y;
  size_t base = (size_t)b * n4;
  float al = scal[OS_ALPHA + b];
  int j = blockIdx.x * blockDim.x + threadIdx.x;
  float part = 0.f;
  if (j < n4){
    float4 pv = ((const float4*)p)[base + j];
    float4 av = ((const float4*)Ap)[base + j];
    float4 xv = ((float4*)x)[base + j];
    float4 rv = ((float4*)r)[base + j];
    xv.x += al * pv.x; xv.y += al * pv.y; xv.z += al * pv.z; xv.w += al * pv.w;
    rv.x -= al * av.x; rv.y -= al * av.y; rv.z -= al * av.z; rv.w -= al * av.w;
    ((float4*)x)[base + j] = xv;
    ((float4*)r)[base + j] = rv;
    part = rv.x*rv.x + rv.y*rv.y + rv.z*rv.z + rv.w*rv.w;
  }
  float tot = blk_reduce_256(part);
  if (threadIdx.x == 0) atomicAdd(&scal[OS_RSNEW + b], tot);
}

__global__ void k_s2_o(float* scal){
  int* flag = (int*)(scal + OS_FLAG);
  if (*flag) return;
  if (threadIdx.x == 0){
    float ssum = 0.f;
    for (int bb = 0; bb < 8; ++bb) ssum += scal[OS_RSNEW + bb];
    if (sqrtf(ssum / 8.0f) < TOL){
      *flag = 1;
    } else {
      for (int bb = 0; bb < 8; ++bb){
        scal[OS_BETA + bb]  = scal[OS_RSNEW + bb] / (scal[OS_RSOLD + bb] + 1e-12f);
        scal[OS_RSOLD + bb] = scal[OS_RSNEW + bb];
        scal[OS_PAP + bb]   = 0.f;
      }
    }
  }
}

__global__ void k_pupd_o(const float* __restrict__ r, float* __restrict__ p,
                         float* scal, int n4){
  const int* flag = (const int*)(scal + OS_FLAG);
  if (*flag) return;
  int b = blockIdx.y;
  size_t base = (size_t)b * n4;
  float be = scal[OS_BETA + b];
  int j = blockIdx.x * blockDim.x + threadIdx.x;
  if (j < n4){
    float4 rv = ((const float4*)r)[base + j];
    float4 pv = ((float4*)p)[base + j];
    pv.x = rv.x + be * pv.x; pv.y = rv.y + be * pv.y;
    pv.z = rv.z + be * pv.z; pv.w = rv.w + be * pv.w;
    ((float4*)p)[base + j] = pv;
  }
}

// ---------------- launch ----------------
extern "C" void kernel_launch(void* const* d_in, const int* in_sizes, int n_in,
                              void* d_out, int out_size, void* d_ws, size_t ws_size,
                              hipStream_t stream){
  const float* c0  = (const float*)d_in[0];
  const int*   src = (const int*)d_in[1];
  const int*   dst = (const int*)d_in[2];
  const float* Rs  = (const float*)d_in[3];
  const float* Rd  = (const float*)d_in[4];

  int N  = in_sizes[0];          // B*Mn*8 floats, B=8, d=8
  int Mn = N / 64;
  int E  = in_sizes[1];
  int n4tot = N / 4;
  int twoE = 2 * E;

  float* ws = (float*)d_ws;
  size_t off = 0;
  float* x_ws = ws + off;  off += N;
  float* r    = ws + off;  off += N;
  float* p    = ws + off;  off += N;
  float* Ap   = ws + off;  off += N;
  float* scal = ws + off;  off += SCAL_F;
  float* D    = ws + off;  off += (size_t)Mn * 64;
  int* rowptr = (int*)(ws + off);  off += (size_t)((Mn + 1 + 3) & ~3);
  int* cursor = (int*)(ws + off);  off += (size_t)((Mn + 3) & ~3);
  int2* pair  = (int2*)(ws + off); off += (size_t)4 * E;     // 2E int2
  float* Mb   = ws + off;  off += (size_t)E * 64;
  size_t need_main = off * 4;

  int nb_vec  = (n4tot + 255) / 256;
  int nb_node = (Mn * 64 + 255) / 256;

  if (ws_size >= need_main){
    k_setup_nm<<<2048, 256, 0, stream>>>(D, scal, cursor, Mn);
    k_deg  <<<1024, 256, 0, stream>>>(src, dst, cursor, E);
    k_scan <<<1, 1024, 0, stream>>>(cursor, rowptr, cursor, Mn, twoE);
    k_fill2<<<1024, 256, 0, stream>>>(src, dst, cursor, pair, E);
    k_edgeM<<<4096, 256, 0, stream>>>(Rs, Rd, src, dst, Mb, D, E);

    k_perm<<<nb_vec, 256, 0, stream>>>(c0, x_ws, Mn);
    k_mv<<<nb_node, 256, 0, stream>>>(D, Mb, rowptr, pair, x_ws, Ap, scal, Mn);
    k_init_nm<<<nb_vec, 256, 0, stream>>>(x_ws, Ap, r, p, scal, n4tot);
    k_s0<<<1, 256, 0, stream>>>(scal);

    for (int it = 0; it < NIT; ++it){
      k_mv<<<nb_node, 256, 0, stream>>>(D, Mb, rowptr, pair, p, Ap, scal, Mn);
      k_upd_nm<<<nb_vec, 256, 0, stream>>>(x_ws, r, p, Ap, scal, n4tot);
      k_s2<<<1, 256, 0, stream>>>(scal);
      k_pupd_nm<<<nb_vec, 256, 0, stream>>>(r, p, scal, n4tot);
    }
    k_export<<<nb_vec, 256, 0, stream>>>(x_ws, (float*)d_out, Mn);
  } else {
    // fallback: batch-major R-direct (needs 3N+64 floats)
    float* fr    = ws;
    float* fp    = fr + N;
    float* fAp   = fp + N;
    float* fscal = fAp + N;
    const int* flagp = (const int*)(fscal + OS_FLAG);
    int n4 = (Mn * 8 * 8) / 8 / 4 * 4;  // per-batch float4 count = Mn*2
    n4 = Mn * 2;
    dim3 vgrid((n4 + 255) / 256, 8);
    int cb = (n4tot + 255) / 256;
    float* x = (float*)d_out;

    k_setup_fb<<<1, 64, 0, stream>>>(fscal);
    k_apinit<<<cb, 256, 0, stream>>>(c0, fAp, n4tot, flagp);
    k_mv_edge_fb<<<2048, 256, 0, stream>>>(Rs, Rd, src, dst, c0, fAp, Mn, E, flagp);
    k_init_o<<<vgrid, 256, 0, stream>>>(c0, fAp, x, fr, fp, fscal, n4);
    for (int it = 0; it < NIT; ++it){
      k_apinit<<<cb, 256, 0, stream>>>(fp, fAp, n4tot, flagp);
      k_mv_edge_fb<<<2048, 256, 0, stream>>>(Rs, Rd, src, dst, fp, fAp, Mn, E, flagp);
      k_dot_o<<<vgrid, 256, 0, stream>>>(fp, fAp, fscal, n4);
      k_s1_o<<<1, 64, 0, stream>>>(fscal);
      k_upd_o<<<vgrid, 256, 0, stream>>>(x, fr, fp, fAp, fscal, n4);
      k_s2_o<<<1, 64, 0, stream>>>(fscal);
      k_pupd_o<<<vgrid, 256, 0, stream>>>(fr, fp, fscal, n4);
    }
  }
}